// Round 4
// baseline (1889.995 us; speedup 1.0000x reference)
//
#include <hip/hip_runtime.h>
#include <math.h>

#define NN 100000
#define DD 128
#define HH 64
#define KK 8
#define LL 3
#define CC 16
#define EE 1600000
#define NB_SCAN 391  // ceil(NN/256)

typedef float v2f __attribute__((ext_vector_type(2)));

// ---------------- CSR build (layer-invariant) ----------------

__global__ __launch_bounds__(256) void deg_kernel(const int* __restrict__ col,
                                                  int* __restrict__ deg) {
  int i = blockIdx.x * 256 + threadIdx.x;  // EE % 256 == 0
  atomicAdd(&deg[col[i]], 1);
}

__global__ __launch_bounds__(256) void dn_kernel(const int* __restrict__ deg,
                                                 float* __restrict__ dn) {
  int i = blockIdx.x * 256 + threadIdx.x;
  if (i < NN) {
    int d = deg[i];
    dn[i] = d > 0 ? 1.0f / sqrtf((float)d) : 0.0f;
  }
}

__global__ __launch_bounds__(256) void scan1_kernel(const int* __restrict__ deg,
                                                    int* __restrict__ offs,
                                                    int* __restrict__ bsum) {
  __shared__ int tmp[256];
  int t = threadIdx.x;
  int i = blockIdx.x * 256 + t;
  int v = (i < NN) ? deg[i] : 0;
  tmp[t] = v;
  __syncthreads();
#pragma unroll
  for (int d = 1; d < 256; d <<= 1) {
    int x = (t >= d) ? tmp[t - d] : 0;
    __syncthreads();
    tmp[t] += x;
    __syncthreads();
  }
  if (i < NN) offs[i] = tmp[t] - v;
  if (t == 255) bsum[blockIdx.x] = tmp[255];
}

__global__ __launch_bounds__(256) void scan2_kernel(int* __restrict__ bsum) {
  __shared__ int tmp[256];
  __shared__ int carry_s;
  int t = threadIdx.x;
  if (t == 0) carry_s = 0;
  __syncthreads();
  for (int base = 0; base < NB_SCAN; base += 256) {
    int i = base + t;
    int v = (i < NB_SCAN) ? bsum[i] : 0;
    tmp[t] = v;
    __syncthreads();
#pragma unroll
    for (int d = 1; d < 256; d <<= 1) {
      int x = (t >= d) ? tmp[t - d] : 0;
      __syncthreads();
      tmp[t] += x;
      __syncthreads();
    }
    int carry = carry_s;
    if (i < NB_SCAN) bsum[i] = carry + tmp[t] - v;
    __syncthreads();
    if (t == 0) carry_s = carry + tmp[255];
    __syncthreads();
  }
}

__global__ __launch_bounds__(256) void scan3_kernel(int* __restrict__ offs,
                                                    const int* __restrict__ bsum) {
  int i = blockIdx.x * 256 + threadIdx.x;
  if (i < NN) offs[i] += bsum[blockIdx.x];
}

__global__ __launch_bounds__(256) void fill_kernel(const int* __restrict__ row,
                                                   const int* __restrict__ col,
                                                   const int* __restrict__ offs,
                                                   int* __restrict__ cursor,
                                                   const float* __restrict__ dn,
                                                   int2* __restrict__ csr) {
  int e = blockIdx.x * 256 + threadIdx.x;  // EE % 256 == 0
  int c = col[e], r = row[e];
  int pos = offs[c] + atomicAdd(&cursor[c], 1);
  int2 p;
  p.x = r;
  p.y = __float_as_int(dn[c] * dn[r]);
  csr[pos] = p;
}

// ---------------- fc0 ----------------

__global__ __launch_bounds__(256) void fc0_kernel(const float* __restrict__ x,
                                                  const float* __restrict__ w,
                                                  const float* __restrict__ b,
                                                  float* __restrict__ h) {
  int id = blockIdx.x * 256 + threadIdx.x;
  int n = id >> 6, o = id & 63;
  const float* xr = x + n * DD;
  float s0 = 0.f, s1 = 0.f, s2 = 0.f, s3 = 0.f;
#pragma unroll
  for (int f = 0; f < DD; f += 4) {
    s0 = fmaf(xr[f + 0], w[(f + 0) * HH + o], s0);
    s1 = fmaf(xr[f + 1], w[(f + 1) * HH + o], s1);
    s2 = fmaf(xr[f + 2], w[(f + 2) * HH + o], s2);
    s3 = fmaf(xr[f + 3], w[(f + 3) * HH + o], s3);
  }
  h[id] = fmaxf((s0 + s1) + (s2 + s3) + b[o], 0.0f);
}

// ---------------- env gate ----------------

__global__ __launch_bounds__(256) void env_kernel(const float* __restrict__ h,
                                                  const float* __restrict__ env_w,
                                                  const float* __restrict__ env_b,
                                                  float* __restrict__ e_out) {
  int n = blockIdx.x * 256 + threadIdx.x;
  if (n >= NN) return;
  float logit[KK];
#pragma unroll
  for (int k = 0; k < KK; ++k) logit[k] = env_b[k];
  const float4* hp = reinterpret_cast<const float4*>(h + n * HH);
#pragma unroll
  for (int f4 = 0; f4 < HH / 4; ++f4) {
    float4 hv = hp[f4];
    float hj[4] = {hv.x, hv.y, hv.z, hv.w};
#pragma unroll
    for (int j = 0; j < 4; ++j) {
      int f = f4 * 4 + j;
#pragma unroll
      for (int k = 0; k < KK; ++k)
        logit[k] = fmaf(hj[j], env_w[f * KK + k], logit[k]);
    }
  }
  float m = logit[0];
#pragma unroll
  for (int k = 1; k < KK; ++k) m = fmaxf(m, logit[k]);
  float p[KK];
  float s = 0.f;
#pragma unroll
  for (int k = 0; k < KK; ++k) {
    p[k] = expf(logit[k] - m);
    s += p[k];
  }
#pragma unroll
  for (int k = 0; k < KK; ++k) {
    float pi = p[k] / s;
    e_out[n * KK + k] = ((double)pi > 0.1) ? pi : 0.0f;
  }
}

// ---------------- GCN gather (CSR, no atomics) ----------------

__global__ __launch_bounds__(256) void gather_kernel(const int2* __restrict__ csr,
                                                     const int* __restrict__ offs,
                                                     const int* __restrict__ deg,
                                                     const float* __restrict__ h,
                                                     float* __restrict__ agg) {
  int n = blockIdx.x * 4 + (threadIdx.x >> 6);
  if (n >= NN) return;
  int lane = threadIdx.x & 63;
  int j = offs[n];
  int end = j + deg[n];
  float a0 = 0.f, a1 = 0.f, a2 = 0.f, a3 = 0.f;
  for (; j + 3 < end; j += 4) {
    int2 p0 = csr[j], p1 = csr[j + 1], p2 = csr[j + 2], p3 = csr[j + 3];
    float h0 = h[p0.x * HH + lane];
    float h1 = h[p1.x * HH + lane];
    float h2 = h[p2.x * HH + lane];
    float h3 = h[p3.x * HH + lane];
    a0 = fmaf(h0, __int_as_float(p0.y), a0);
    a1 = fmaf(h1, __int_as_float(p1.y), a1);
    a2 = fmaf(h2, __int_as_float(p2.y), a2);
    a3 = fmaf(h3, __int_as_float(p3.y), a3);
  }
  for (; j < end; ++j) {
    int2 p = csr[j];
    a0 = fmaf(h[p.x * HH + lane], __int_as_float(p.y), a0);
  }
  agg[n * HH + lane] = (a0 + a1) + (a2 + a3);
}

// ---------------- dense register-blocked conv ----------------
// Block: 256 threads = 4 waves, 64 nodes. Wave: 16 nodes (2 groups of 8).
// Lane = (g = node-slot 0..7, i = o-oct 0..7). All 8 heads computed densely;
// gating folded as out += e[k] * head_acc (e==0 kills inactive heads exactly
// like the reference einsum). Weights live in VGPRs per f-chunk of 8, reused
// across the wave's 16 nodes -> L2 weight traffic 11.5 GB -> 0.4 GB/layer.
// his rows padded to 132 floats: group-broadcast ds_read_b128 covers all 32
// banks exactly once (conflict-free).

__global__ __launch_bounds__(256) void conv_kernel(float* __restrict__ h,
                                                   const float* __restrict__ agg,
                                                   const float* __restrict__ eg,
                                                   const float* __restrict__ w) {
  __shared__ float his[64][132];  // [node][ agg(0..63) | h(64..127) ], pad 4
  __shared__ float es[64][8];

  int t = threadIdx.x;
  int nb = blockIdx.x * 64;

  // stage hi = [agg || h] for 64 nodes (zeros for OOB)
#pragma unroll
  for (int r = 0; r < 8; ++r) {
    int lin = r * 256 + t;    // 0..2047
    int ln = lin >> 5;        // local node
    int slot = lin & 31;      // 16 agg float4 + 16 h float4
    int n = nb + ln;
    float4 v = make_float4(0.f, 0.f, 0.f, 0.f);
    if (n < NN) {
      const float* src = (slot < 16) ? (agg + n * HH + slot * 4)
                                     : (h + n * HH + (slot - 16) * 4);
      v = *reinterpret_cast<const float4*>(src);
    }
    int off = (slot < 16) ? slot * 4 : 64 + (slot - 16) * 4;
    *reinterpret_cast<float4*>(&his[ln][off]) = v;
  }
  // stage e
  if (t < 128) {
    int ln = t >> 1, half = t & 1;
    int n = nb + ln;
    float4 v = make_float4(0.f, 0.f, 0.f, 0.f);
    if (n < NN) v = *reinterpret_cast<const float4*>(eg + n * KK + half * 4);
    *reinterpret_cast<float4*>(&es[ln][half * 4]) = v;
  }
  __syncthreads();

  int wv = t >> 6, lane = t & 63;
  int g = lane >> 3, i = lane & 7;
  int lnA = wv * 16 + g, lnB = lnA + 8;
  int obase = i * 8;

  v2f outA[4], outB[4];
#pragma unroll
  for (int p = 0; p < 4; ++p) { outA[p] = (v2f)0.f; outB[p] = (v2f)0.f; }

  const float* wk = w + obase;  // + k*8192 + f*64
  for (int k = 0; k < KK; ++k) {
    v2f hA[4], hB[4];
#pragma unroll
    for (int p = 0; p < 4; ++p) { hA[p] = (v2f)0.f; hB[p] = (v2f)0.f; }

#pragma unroll 4
    for (int chunk = 0; chunk < 16; ++chunk) {
      // weight f-chunk (8 f) into registers: reused by both node groups
      v2f wreg[8][4];
#pragma unroll
      for (int j = 0; j < 8; ++j) {
        const v2f* wrow = reinterpret_cast<const v2f*>(wk + (chunk * 8 + j) * HH);
#pragma unroll
        for (int q = 0; q < 4; ++q) wreg[j][q] = wrow[q];
      }
#pragma unroll
      for (int fq = 0; fq < 2; ++fq) {
        float4 ha = *reinterpret_cast<const float4*>(&his[lnA][chunk * 8 + fq * 4]);
        float4 hb = *reinterpret_cast<const float4*>(&his[lnB][chunk * 8 + fq * 4]);
        float av[4] = {ha.x, ha.y, ha.z, ha.w};
        float bv[4] = {hb.x, hb.y, hb.z, hb.w};
#pragma unroll
        for (int j2 = 0; j2 < 4; ++j2) {
          int j = fq * 4 + j2;
#pragma unroll
          for (int p = 0; p < 4; ++p) {
            hA[p] += wreg[j][p] * av[j2];
            hB[p] += wreg[j][p] * bv[j2];
          }
        }
      }
    }
    float eA = es[lnA][k], eB = es[lnB][k];
#pragma unroll
    for (int p = 0; p < 4; ++p) {
      outA[p] += hA[p] * eA;
      outB[p] += hB[p] * eB;
    }
    wk += 2 * HH * HH;
  }

  // epilogue: out = relu(h + gated conv), in place
  int nA = nb + lnA, nB = nb + lnB;
  if (nA < NN) {
    float4 r0, r1;
    r0.x = fmaxf(his[lnA][64 + obase + 0] + outA[0][0], 0.f);
    r0.y = fmaxf(his[lnA][64 + obase + 1] + outA[0][1], 0.f);
    r0.z = fmaxf(his[lnA][64 + obase + 2] + outA[1][0], 0.f);
    r0.w = fmaxf(his[lnA][64 + obase + 3] + outA[1][1], 0.f);
    r1.x = fmaxf(his[lnA][64 + obase + 4] + outA[2][0], 0.f);
    r1.y = fmaxf(his[lnA][64 + obase + 5] + outA[2][1], 0.f);
    r1.z = fmaxf(his[lnA][64 + obase + 6] + outA[3][0], 0.f);
    r1.w = fmaxf(his[lnA][64 + obase + 7] + outA[3][1], 0.f);
    *reinterpret_cast<float4*>(h + nA * HH + obase) = r0;
    *reinterpret_cast<float4*>(h + nA * HH + obase + 4) = r1;
  }
  if (nB < NN) {
    float4 r0, r1;
    r0.x = fmaxf(his[lnB][64 + obase + 0] + outB[0][0], 0.f);
    r0.y = fmaxf(his[lnB][64 + obase + 1] + outB[0][1], 0.f);
    r0.z = fmaxf(his[lnB][64 + obase + 2] + outB[1][0], 0.f);
    r0.w = fmaxf(his[lnB][64 + obase + 3] + outB[1][1], 0.f);
    r1.x = fmaxf(his[lnB][64 + obase + 4] + outB[2][0], 0.f);
    r1.y = fmaxf(his[lnB][64 + obase + 5] + outB[2][1], 0.f);
    r1.z = fmaxf(his[lnB][64 + obase + 6] + outB[3][0], 0.f);
    r1.w = fmaxf(his[lnB][64 + obase + 7] + outB[3][1], 0.f);
    *reinterpret_cast<float4*>(h + nB * HH + obase) = r0;
    *reinterpret_cast<float4*>(h + nB * HH + obase + 4) = r1;
  }
}

// ---------------- fc1 ----------------

__global__ __launch_bounds__(256) void fc1_kernel(const float* __restrict__ h,
                                                  const float* __restrict__ w,
                                                  const float* __restrict__ b,
                                                  float* __restrict__ out) {
  int id = blockIdx.x * 256 + threadIdx.x;
  int n = id >> 4, c = id & 15;
  const float* hr = h + n * HH;
  float acc = b[c];
#pragma unroll
  for (int o = 0; o < HH; ++o) acc = fmaf(hr[o], w[o * CC + c], acc);
  out[id] = acc;
}

// ---------------- launch ----------------

extern "C" void kernel_launch(void* const* d_in, const int* in_sizes, int n_in,
                              void* d_out, int out_size, void* d_ws, size_t ws_size,
                              hipStream_t stream) {
  const float* x      = (const float*)d_in[0];
  const int*   ei     = (const int*)d_in[1];
  const float* fc0_w  = (const float*)d_in[2];
  const float* fc0_b  = (const float*)d_in[3];
  const float* fc1_w  = (const float*)d_in[4];
  const float* fc1_b  = (const float*)d_in[5];
  const float* env_w  = (const float*)d_in[6];
  const float* env_b  = (const float*)d_in[7];
  const float* conv_w = (const float*)d_in[8];
  float* out = (float*)d_out;

  float* ws   = (float*)d_ws;
  float* h    = ws;                        // 6,400,000
  float* agg  = ws + 6400000;              // 6,400,000
  float* e_g  = ws + 12800000;             // 800,000
  float* dn   = ws + 13600000;             // 100,000
  int*   degi = (int*)(ws + 13700000);     // 100,000
  int*   offs = (int*)(ws + 13800000);     // 100,000
  int*   curs = (int*)(ws + 13900000);     // 100,000
  int*   bsum = (int*)(ws + 14000000);     // 1,024
  int2*  csr  = (int2*)(ws + 14002000);    // 1,600,000 * 8B

  const int* row = ei;
  const int* col = ei + EE;

  hipMemsetAsync(degi, 0, NN * sizeof(int), stream);
  hipMemsetAsync(curs, 0, NN * sizeof(int), stream);
  deg_kernel<<<EE / 256, 256, 0, stream>>>(col, degi);
  dn_kernel<<<NB_SCAN, 256, 0, stream>>>(degi, dn);
  scan1_kernel<<<NB_SCAN, 256, 0, stream>>>(degi, offs, bsum);
  scan2_kernel<<<1, 256, 0, stream>>>(bsum);
  scan3_kernel<<<NB_SCAN, 256, 0, stream>>>(offs, bsum);
  fill_kernel<<<EE / 256, 256, 0, stream>>>(row, col, offs, curs, dn, csr);

  fc0_kernel<<<(NN * HH) / 256, 256, 0, stream>>>(x, fc0_w, fc0_b, h);

  for (int l = 0; l < LL; ++l) {
    env_kernel<<<NB_SCAN, 256, 0, stream>>>(
        h, env_w + l * (2 * HH * KK), env_b + l * KK, e_g);
    gather_kernel<<<(NN + 3) / 4, 256, 0, stream>>>(csr, offs, degi, h, agg);
    conv_kernel<<<(NN + 63) / 64, 256, 0, stream>>>(
        h, agg, e_g, conv_w + l * (KK * 2 * HH * HH));
  }

  fc1_kernel<<<(NN * CC) / 256, 256, 0, stream>>>(h, fc1_w, fc1_b, out);
}